// Round 1
// baseline (1411.225 us; speedup 1.0000x reference)
//
#include <hip/hip_runtime.h>
#include <hip/hip_bf16.h>
#include <math.h>

// Problem constants
#define BB   64
#define TT   2048
#define DD   8        // LATENT
#define HH   64       // HID
#define LLEN 2046     // length = TT - LAGS
#define NN   (BB*LLEN) // 130944
#define GIN  81       // HID + LAGS*LATENT + 1

// ---------------------------------------------------------------------------
// Generic fused GEMV layer: zr (LDS row, K inputs) -> zr (64 outputs)
// Weights are wave-uniform (address depends only on block index / loop
// counters) -> compiler should promote to s_load.
// ---------------------------------------------------------------------------
template<int K, bool ACT>
__device__ __forceinline__ void fwd_layer(float* zr,
                                          const float* __restrict__ W,
                                          const float* __restrict__ bias)
{
    float acc[HH];
#pragma unroll
    for (int j = 0; j < HH; ++j) acc[j] = bias[j];
    for (int k = 0; k < K; ++k) {
        const float zk = zr[k];
        const float* wr = W + k * HH;
#pragma unroll
        for (int j = 0; j < HH; ++j) acc[j] = fmaf(zk, wr[j], acc[j]);
    }
#pragma unroll
    for (int j = 0; j < HH; ++j) {
        float v = acc[j];
        if (ACT) v = (v >= 0.f) ? v : 0.1f * v;
        zr[j] = v;
    }
}

// ---------------------------------------------------------------------------
// Kernel A: embedding MLP (8 -> 64 -> 64 -> 64 -> 64), thread per (b,t)
// Writes embN[n][64] to workspace. Grid: 682 blocks x 192 threads (exact).
// ---------------------------------------------------------------------------
__global__ __launch_bounds__(192) void emb_mlp_kernel(
    const float* __restrict__ emb_in,
    const float* __restrict__ W1, const float* __restrict__ b1,
    const float* __restrict__ Wh, const float* __restrict__ bh,
    const float* __restrict__ W2, const float* __restrict__ b2,
    float* __restrict__ embN)
{
    __shared__ float zrow[192][65];   // odd stride -> 2-way bank alias (free)
    const int tid = threadIdx.x;
    const int n = blockIdx.x * 192 + tid;          // grid exact: 682*192 == NN
    const int b = n / LLEN;
    const int l = n - b * LLEN;
    float* zr = zrow[tid];

    const float* ep = emb_in + ((size_t)(b * TT + (l + 2))) * 8;
    {
        float4 e0 = *(const float4*)ep;
        float4 e1 = *(const float4*)(ep + 4);
        zr[0] = e0.x; zr[1] = e0.y; zr[2] = e0.z; zr[3] = e0.w;
        zr[4] = e1.x; zr[5] = e1.y; zr[6] = e1.z; zr[7] = e1.w;
    }

    fwd_layer<8,  true >(zr, W1, b1);
    fwd_layer<HH, true >(zr, Wh,            bh);
    fwd_layer<HH, true >(zr, Wh + HH * HH,  bh + HH);
    fwd_layer<HH, false>(zr, W2, b2);

    float* op = embN + (size_t)n * HH;
#pragma unroll
    for (int j = 0; j < HH; j += 4) {
        float4 v = { zr[j], zr[j+1], zr[j+2], zr[j+3] };
        *(float4*)(op + j) = v;
    }
}

// ---------------------------------------------------------------------------
// Kernel B: per-(n, d) g-MLP forward + JVP.
// blockIdx.y = d (weights wave-uniform). Block = 64 threads (1 wave).
// LDS: z row (81 floats) + dh row (65 floats) per thread = 37.4 KB/block.
// ---------------------------------------------------------------------------
__global__ __launch_bounds__(64) void gmlp_kernel(
    const float* __restrict__ x,
    const float* __restrict__ embN,
    const float* __restrict__ gW1, const float* __restrict__ gb1,
    const float* __restrict__ gWh, const float* __restrict__ gbh,
    const float* __restrict__ gW2, const float* __restrict__ gb2,
    float* __restrict__ resid, float* __restrict__ logd)
{
    __shared__ float zrow[64][GIN];   // 81 floats (odd stride)
    __shared__ float drow[64][65];
    const int tid = threadIdx.x;
    const int d = blockIdx.y;
    const int n = blockIdx.x * 64 + tid;           // grid exact: 2046*64 == NN
    const int b = n / LLEN;
    const int l = n - b * LLEN;
    float* zr = zrow[tid];
    float* dr = drow[tid];

    // ---- assemble input z = [emb(64), x_lags(16), x_t[d]] ----
    const float* ebp = embN + (size_t)n * HH;
#pragma unroll
    for (int k = 0; k < HH; k += 4) {
        float4 v = *(const float4*)(ebp + k);
        zr[k] = v.x; zr[k+1] = v.y; zr[k+2] = v.z; zr[k+3] = v.w;
    }
    const float* xp = x + ((size_t)(b * TT + l)) * DD;
#pragma unroll
    for (int k = 0; k < 16; k += 4) {
        float4 v = *(const float4*)(xp + k);
        zr[64+k] = v.x; zr[64+k+1] = v.y; zr[64+k+2] = v.z; zr[64+k+3] = v.w;
    }
    zr[80] = xp[16 + d];

    // ---- layer 1: 81 -> 64, forward only; JVP seed from last weight row ----
    const float* W1 = gW1 + (size_t)d * GIN * HH;
    fwd_layer<GIN, true>(zr, W1, gb1 + d * HH);
    const float* wlast = W1 + 80 * HH;
#pragma unroll
    for (int j = 0; j < HH; ++j) {
        // sign(h1) == sign(pre1) for leaky with slope 0.1
        float m = (zr[j] >= 0.f) ? 1.f : 0.1f;
        dr[j] = wlast[j] * m;
    }

    // ---- hidden layers: fused forward + JVP (shared weight loads) ----
    for (int jj = 0; jj < 2; ++jj) {
        const float* W  = gWh + ((size_t)d * 2 + jj) * HH * HH;
        const float* bb = gbh + (d * 2 + jj) * HH;
        float facc[HH], jacc[HH];
#pragma unroll
        for (int j = 0; j < HH; ++j) { facc[j] = bb[j]; jacc[j] = 0.f; }
        for (int k = 0; k < HH; ++k) {
            const float zk = zr[k];
            const float dk = dr[k];
            const float* wr = W + k * HH;
#pragma unroll
            for (int j = 0; j < HH; ++j) {
                const float w = wr[j];
                facc[j] = fmaf(zk, w, facc[j]);
                jacc[j] = fmaf(dk, w, jacc[j]);
            }
        }
#pragma unroll
        for (int j = 0; j < HH; ++j) {
            float m = (facc[j] >= 0.f) ? 1.f : 0.1f;
            zr[j] = facc[j] * m;       // == leaky(facc)
            dr[j] = jacc[j] * m;
        }
    }

    // ---- final layer: 64 -> 1 ----
    const float* w2 = gW2 + d * HH;
    float o = gb2[d], dq = 0.f;
    for (int k = 0; k < HH; ++k) {
        o  = fmaf(zr[k], w2[k], o);
        dq = fmaf(dr[k], w2[k], dq);
    }
    resid[(size_t)n * DD + d] = o;
    logd[(size_t)d * NN + n] = logf(fabsf(dq));
}

// ---------------------------------------------------------------------------
// Kernel C: log-det reduction over d
// ---------------------------------------------------------------------------
__global__ __launch_bounds__(256) void reduce_kernel(
    const float* __restrict__ logd, float* __restrict__ out)
{
    const int n = blockIdx.x * 256 + threadIdx.x;
    if (n >= NN) return;
    float s = 0.f;
#pragma unroll
    for (int d = 0; d < DD; ++d) s += logd[(size_t)d * NN + n];
    out[n] = s;
}

extern "C" void kernel_launch(void* const* d_in, const int* in_sizes, int n_in,
                              void* d_out, int out_size, void* d_ws, size_t ws_size,
                              hipStream_t stream)
{
    const float* x          = (const float*)d_in[0];
    const float* embeddings = (const float*)d_in[1];
    const float* fcW1 = (const float*)d_in[2];
    const float* fcb1 = (const float*)d_in[3];
    const float* fcWh = (const float*)d_in[4];
    const float* fcbh = (const float*)d_in[5];
    const float* fcW2 = (const float*)d_in[6];
    const float* fcb2 = (const float*)d_in[7];
    const float* gW1  = (const float*)d_in[8];
    const float* gb1  = (const float*)d_in[9];
    const float* gWh  = (const float*)d_in[10];
    const float* gbh  = (const float*)d_in[11];
    const float* gW2  = (const float*)d_in[12];
    const float* gb2  = (const float*)d_in[13];

    float* out  = (float*)d_out;
    float* embN = (float*)d_ws;                         // NN*64 floats
    float* logd = embN + (size_t)NN * HH;               // NN*8 floats

    emb_mlp_kernel<<<dim3(NN / 192), 192, 0, stream>>>(
        embeddings, fcW1, fcb1, fcWh, fcbh, fcW2, fcb2, embN);

    gmlp_kernel<<<dim3(NN / 64, DD), 64, 0, stream>>>(
        x, embN, gW1, gb1, gWh, gbh, gW2, gb2, out, logd);

    reduce_kernel<<<dim3((NN + 255) / 256), 256, 0, stream>>>(
        logd, out + (size_t)NN * DD);
}